// Round 1
// baseline (101.061 us; speedup 1.0000x reference)
//
#include <hip/hip_runtime.h>
#include <hip/hip_bf16.h>

// VQ-VAE quantizer, MI355X. bf16-MFMA distance GEMM.
// v2: codebook fragments staged in LDS (64 KB, global_load_lds w=16, shared by
// all 4 waves), rt=4 (64 px/wave, 256 px/block, grid 512), codebook pre-scaled
// by -2 with e2 folded into the MFMA C-operand (one VALU op less per score).
// latents: [B=32, D=64, H=64, W=64] fp32 ; embedding: [K=512, D=64] fp32
// out: quantized [B,D,H,W] fp32 (8388608) then vq_loss scalar (1).
// loss = 1.25 * mean(||x||^2 + (||e||^2 - 2 x.e_best))

#define VQ_K 512
#define VQ_D 64
#define VQ_HW 4096
#define VQ_N 131072
#define VQ_ELEMS 8388608

typedef float f32x4 __attribute__((ext_vector_type(4)));
typedef __bf16 bf16x8 __attribute__((ext_vector_type(8)));

// ws layout (bytes):
//   [0,      65536) : codebook * (-2) in bf16 B-fragment order (64 chunks of 1 KB)
//   [65536,  67584) : e2p[512] = ||e_k||^2 + 0.5
//   [67584,  69632) : loss partials[512]

// ---- prep: bf16 (-2*e) fragments + squared norms ---------------------------
__global__ __launch_bounds__(256) void vq_prep(
    const float* __restrict__ emb, uint32_t* __restrict__ bfrag,
    float* __restrict__ e2p)
{
  const int tid = threadIdx.x;
  if (blockIdx.x < 16) {
    const int gid  = blockIdx.x * 256 + tid;     // 0..4095
    const int lane = gid & 63, ckh = gid >> 6;   // ckh = ct*2 + kh
    const int ct = ckh >> 1, kh = ckh & 1;
    const int code  = ct * 16 + (lane & 15);     // B-frag: n = lane&15
    const int dbase = kh * 32 + (lane >> 4) * 8; // k = kh*32 + quad*8 + j
    const float* src = emb + code * VQ_D + dbase;
    uint32_t wds[4];
    #pragma unroll
    for (int jj = 0; jj < 4; ++jj) {
      // -2x is exact in bf16 (power-of-2 scale): scores come out of MFMA直接
      float2 f2; f2.x = -2.f * src[2 * jj]; f2.y = -2.f * src[2 * jj + 1];
      __hip_bfloat162 bb = __float22bfloat162_rn(f2);
      wds[jj] = *(const uint32_t*)&bb;
    }
    uint4 v; v.x = wds[0]; v.y = wds[1]; v.z = wds[2]; v.w = wds[3];
    *(uint4*)&bfrag[gid * 4] = v;
  } else {
    for (int cc = tid; cc < VQ_K; cc += 256) {
      const float* src = emb + cc * VQ_D;
      float s = 0.f;
      #pragma unroll
      for (int d = 0; d < VQ_D; ++d) s = fmaf(src[d], src[d], s);
      e2p[cc] = s + 0.5f;   // +0.5 keeps packed-score trick consistent
    }
  }
}

// ---- main: LDS codebook + MFMA scores + packed argmin + gather + loss ------
// 512 blocks x 256 threads; block = 256 pixels; wave = 64 pixels (rt=4).
__global__ __launch_bounds__(256, 2) void vq_main(
    const float* __restrict__ lat, const float* __restrict__ emb,
    const uint32_t* __restrict__ bfrag_g, const float* __restrict__ e2p_g,
    float* __restrict__ out, float* __restrict__ partial)
{
  __shared__ uint32_t bfrag_s[16384];  // 64 KB, consumption-order (linear)
  __shared__ float    e2s[VQ_K];       // 2 KB
  __shared__ uint32_t bestp[256];
  __shared__ float    wred[4];

  const int tid  = threadIdx.x;
  const int lane = tid & 63;
  const int w    = tid >> 6;
  const int lane15 = lane & 15;
  const int quad   = lane >> 4;

  // 1) async codebook -> LDS DMA, 16B/lane x16: dest is wave-uniform base +
  //    lane*16 (linear), source is the same gid order prep wrote. Overlaps
  //    with the A-staging below; __syncthreads drains vmcnt.
  #pragma unroll
  for (int i = 0; i < 16; ++i) {
    const uint32_t* g = bfrag_g + (i * 256 + tid) * 4;
    uint32_t* l = &bfrag_s[(i * 256 + w * 64) * 4];
    __builtin_amdgcn_global_load_lds(
        (const __attribute__((address_space(1))) void*)g,
        (__attribute__((address_space(3))) void*)l, 16, 0, 0);
  }

  // 2) e2 -> LDS (through-VGPR path, separate region from the DMA)
  e2s[tid]       = e2p_g[tid];
  e2s[tid + 256] = e2p_g[tid + 256];

  // 3) A fragments straight from global in MFMA-A layout + fp32 ||x||^2.
  const int bimg = blockIdx.x >> 4;
  const int hw0  = (blockIdx.x & 15) << 8;
  const float* latb = lat + (size_t)bimg * (VQ_D * VQ_HW) + hw0;
  bf16x8 af[4][2];
  float x2part = 0.f;
  #pragma unroll
  for (int rt = 0; rt < 4; ++rt) {
    const int pix = (w * 4 + rt) * 16 + lane15;         // pixel within block
    const float* base = latb + pix + quad * 8 * VQ_HW;  // d = quad*8 + ...
    #pragma unroll
    for (int kh = 0; kh < 2; ++kh) {
      uint32_t wds[4];
      #pragma unroll
      for (int jj = 0; jj < 4; ++jj) {
        const float v0 = base[(kh * 32 + jj * 2    ) * VQ_HW];
        const float v1 = base[(kh * 32 + jj * 2 + 1) * VQ_HW];
        x2part = fmaf(v0, v0, fmaf(v1, v1, x2part));
        float2 f2; f2.x = v0; f2.y = v1;
        __hip_bfloat162 bb = __float22bfloat162_rn(f2);
        wds[jj] = *(const uint32_t*)&bb;
      }
      uint32_t tmp[4] = {wds[0], wds[1], wds[2], wds[3]};
      af[rt][kh] = *(const bf16x8*)tmp;
    }
  }

  __syncthreads();   // DMA + e2s visible

  const bf16x8* bls = (const bf16x8*)bfrag_s;  // frag (ct,kh): bls[(ct*2+kh)*64+lane]
  bf16x8 b0 = bls[0 * 64 + lane];
  bf16x8 b1 = bls[1 * 64 + lane];

  float mins[4][4];
  #pragma unroll
  for (int rt = 0; rt < 4; ++rt)
    #pragma unroll
    for (int r = 0; r < 4; ++r) mins[rt][r] = 3.0e38f;

  // barrier-free K-loop over 32 code-tiles, LDS-fed, depth-1 register prefetch
  #pragma unroll 2
  for (int ct = 0; ct < 32; ++ct) {
    const int ctn = (ct < 31) ? ct + 1 : 31;
    bf16x8 n0 = bls[(ctn * 2 + 0) * 64 + lane];
    bf16x8 n1 = bls[(ctn * 2 + 1) * 64 + lane];

    const float e2v = e2s[ct * 16 + lane15];
    const uint32_t ucode = (uint32_t)(ct * 16 + lane15);
    #pragma unroll
    for (int rt = 0; rt < 4; ++rt) {
      f32x4 acc = (f32x4)(e2v);   // C-in = ||e||^2+0.5 ; B is -2e -> acc = score
      acc = __builtin_amdgcn_mfma_f32_16x16x32_bf16(af[rt][0], b0, acc, 0, 0, 0);
      acc = __builtin_amdgcn_mfma_f32_16x16x32_bf16(af[rt][1], b1, acc, 0, 0, 0);
      #pragma unroll
      for (int r = 0; r < 4; ++r) {
        const uint32_t pk = (__float_as_uint(acc[r]) & 0xFFFFFE00u) | ucode;
        mins[rt][r] = fminf(mins[rt][r], __uint_as_float(pk));
      }
    }
    b0 = n0; b1 = n1;
  }

  // argmin across the 16 columns of each quad (C: col=lane&15, row=quad*4+r)
  #pragma unroll
  for (int off = 1; off < 16; off <<= 1)
    #pragma unroll
    for (int rt = 0; rt < 4; ++rt)
      #pragma unroll
      for (int r = 0; r < 4; ++r) {
        const float o = __shfl_xor(mins[rt][r], off, 64);
        mins[rt][r] = fminf(mins[rt][r], o);
      }
  if (lane15 == 0) {
    #pragma unroll
    for (int rt = 0; rt < 4; ++rt)
      #pragma unroll
      for (int r = 0; r < 4; ++r)
        bestp[(w * 4 + rt) * 16 + quad * 4 + r] = __float_as_uint(mins[rt][r]);
  }
  __syncthreads();

  // epilogue: 1 thread per pixel, gather 64 dims from fp32 emb, scalar stores
  const uint32_t u = bestp[tid];
  const int code = (int)(u & 511u);
  float lossc = x2part + (__uint_as_float(u & 0xFFFFFE00u) - 0.5f);

  const float4* q4 = (const float4*)(emb + code * VQ_D);
  float* outp = out + (size_t)bimg * (VQ_D * VQ_HW) + hw0 + tid;
  #pragma unroll
  for (int i = 0; i < 16; ++i) {
    const float4 qv = q4[i];
    outp[(i * 4 + 0) * VQ_HW] = qv.x;
    outp[(i * 4 + 1) * VQ_HW] = qv.y;
    outp[(i * 4 + 2) * VQ_HW] = qv.z;
    outp[(i * 4 + 3) * VQ_HW] = qv.w;
  }

  #pragma unroll
  for (int off = 32; off > 0; off >>= 1) lossc += __shfl_down(lossc, off, 64);
  if (lane == 0) wred[w] = lossc;
  __syncthreads();
  if (tid == 0) partial[blockIdx.x] = wred[0] + wred[1] + wred[2] + wred[3];
}

__global__ __launch_bounds__(64) void vq_loss_kernel(
    const float* __restrict__ partial, float* __restrict__ loss_out)
{
  const int tid = threadIdx.x;
  float s = 0.f;
  #pragma unroll
  for (int i = 0; i < 8; ++i) s += partial[tid + i * 64];
  #pragma unroll
  for (int off = 32; off > 0; off >>= 1) s += __shfl_down(s, off, 64);
  if (tid == 0) *loss_out = 1.25f * s / (float)VQ_ELEMS;
}

extern "C" void kernel_launch(void* const* d_in, const int* in_sizes, int n_in,
                              void* d_out, int out_size, void* d_ws, size_t ws_size,
                              hipStream_t stream) {
  const float* lat = (const float*)d_in[0];
  const float* emb = (const float*)d_in[1];
  float* out = (float*)d_out;

  uint32_t* bfrag = (uint32_t*)d_ws;
  float* e2p      = (float*)((char*)d_ws + 65536);
  float* partial  = (float*)((char*)d_ws + 67584);

  vq_prep<<<17, 256, 0, stream>>>(emb, bfrag, e2p);
  vq_main<<<VQ_N / 256, 256, 0, stream>>>(lat, emb, bfrag, e2p, out, partial);
  vq_loss_kernel<<<1, 64, 0, stream>>>(partial, out + (size_t)VQ_ELEMS);
}